// Round 14
// baseline (220.373 us; speedup 1.0000x reference)
//
#include <hip/hip_runtime.h>
#include <hip/hip_bf16.h>
#include <math.h>

// Round 14: edge_mlp build de-VALU.
//   raw A-fragments = original ns bf16 bits (plain loads, no per-element cvt);
//   cut folded into the normalize affine: a = g*(cut*rs*w) + (b - mu*rs*w).
//   Stats still fp32 from g*cut. Bessel chunk (kk=8) unchanged.
// Rest = round-13 structure.

#define PI_F 3.14159265358979323846f

typedef short  short8 __attribute__((ext_vector_type(8)));
typedef short  short4v __attribute__((ext_vector_type(4)));
typedef float  f32x4 __attribute__((ext_vector_type(4)));

static __device__ __forceinline__ float silu_f(float x) {
  return x / (1.0f + __expf(-x));
}
static __device__ __forceinline__ short f2bf(float x) {
  __hip_bfloat16 h = __float2bfloat16(x);
  return *reinterpret_cast<short*>(&h);
}
static __device__ __forceinline__ float bf2f(short s) {
  __hip_bfloat16 h = *reinterpret_cast<__hip_bfloat16*>(&s);
  return __bfloat162float(h);
}

// ---------------------------------------------------------------- prep fused
// blocks [0,85): weight frags | [85,87): norm table | [87,..): receiver hist
__global__ __launch_bounds__(256)
void prep_fused(const float* __restrict__ W1, const float* __restrict__ W2,
                const float* __restrict__ W3, const float* __restrict__ W4,
                const float* __restrict__ Wsc, const float* __restrict__ Wu0,
                const float* __restrict__ Wu1,
                const float* __restrict__ Wo0, const float* __restrict__ Wo1,
                const float* __restrict__ snw, const float* __restrict__ snb,
                const float* __restrict__ snmw, const float* __restrict__ snvw,
                const float* __restrict__ snrm, const float* __restrict__ snrv,
                const int* __restrict__ eidx,
                short* __restrict__ frags, float4* __restrict__ nrm_c,
                int* __restrict__ cnt, int E)
{
  const int b = blockIdx.x;
  if (b < 85) {
    int t = b * 256 + threadIdx.x;
    if (t >= 340 * 64) return;
    int frag = t >> 6, lane = t & 63;
    const float* W; int K, Nout, kk, nt; float scale;
    if (frag < 36)       { int f = frag;       W = W1; K = 265; Nout = 64;  kk = f >> 2; nt = f & 3;  scale = 1.0f / sqrtf(265.0f); }
    else if (frag < 44)  { int f = frag - 36;  W = W2; K = 64;  Nout = 64;  kk = f >> 2; nt = f & 3;  scale = 0.125f; }
    else if (frag < 52)  { int f = frag - 44;  W = W3; K = 64;  Nout = 64;  kk = f >> 2; nt = f & 3;  scale = 0.125f; }
    else if (frag < 116) { int f = frag - 52;  W = W4; K = 64;  Nout = 512; kk = f >> 5; nt = f & 31;
                           scale = 0.125f * ((nt >= 24) ? 0.57735026918962576f : 1.0f); }
    else if (frag < 212) { int f = frag - 116; int m = f >> 5; kk = (f >> 3) & 3; nt = f & 7;
                           W = (m == 0) ? Wsc : ((m == 1) ? Wu0 : Wu1);
                           K = 128; Nout = 128; scale = 0.088388347648318447f; }
    else if (frag < 276) { int f = frag - 212; W = Wo0; K = 256; Nout = 128; kk = f >> 3; nt = f & 7;
                           scale = 1.0f / 256.0f; }
    else                 { int f = frag - 276; W = Wo1; K = 256; Nout = 128; kk = f >> 3; nt = f & 7;
                           scale = 1.0f / 256.0f; }
    int n = nt * 16 + (lane & 15);
    short* out = frags + ((size_t)(frag * 64 + lane)) * 8;
#pragma unroll
    for (int i = 0; i < 8; i++) {
      int k = kk * 32 + ((lane >> 4) << 3) + i;
      float v = (k < K) ? W[(size_t)k * Nout + n] * scale : 0.0f;
      out[i] = f2bf(v);
    }
  } else if (b < 87) {
    int k = (b - 85) * 256 + threadIdx.x;
    float msm0 = 1.0f / (1.0f + __expf(snmw[1] - snmw[0]));
    float vsm0 = 1.0f / (1.0f + __expf(snvw[1] - snvw[0]));
    if (k < 265) {
      float4 c;
      c.x = (1.0f - msm0) * snrm[k];
      c.y = (1.0f - vsm0) * snrv[k] + 1e-5f;
      c.z = snw[k];
      c.w = snb[k];
      nrm_c[k] = c;
    } else if (k == 265) {
      float4 c; c.x = msm0; c.y = vsm0; c.z = 0.f; c.w = 0.f;
      nrm_c[k] = c;
    }
  } else {
    int e = (b - 87) * 256 + threadIdx.x;
    if (e < E) atomicAdd(&cnt[eidx[E + e]], 1);
  }
}

// ---------------------------------------------------------------- node MFMA
#define NPW 16
__global__ __launch_bounds__(128)
void node_mfma(const float* __restrict__ nf, const short* __restrict__ frags,
               short* __restrict__ ns_bf, short4v* __restrict__ suvu, int N)
{
  __shared__ __align__(16) short sA[2][16][520];   // [wave][node][s|vx|vy|vz], +8 pad

  const int tid = threadIdx.x, lane = tid & 63, w = tid >> 6;
  const int nbase = blockIdx.x * (2 * NPW) + w * NPW;

  for (int it = 0; it < 32; ++it) {
    int idx = it * 64 + lane;
    int nd  = idx >> 7;
    int c4  = (idx & 127) << 2;
    int gn  = nbase + nd; if (gn >= N) gn = N - 1;
    float4 g = *(const float4*)&nf[(size_t)gn * 512 + c4];
#pragma unroll
    for (int i = 0; i < 4; i++) {
      int c = c4 + i;
      int pos;
      if (c < 128) pos = c;
      else { int j = c - 128; int u = j / 3, d = j - 3 * u; pos = 128 + (d << 7) + u; }
      sA[w][nd][pos] = f2bf(((const float*)&g)[i]);
    }
  }
  __syncthreads();

  const int arow = lane & 15;
  const int kgrp = (lane >> 4) << 3;
  short8 af[4][4];
#pragma unroll
  for (int m = 0; m < 4; m++)
#pragma unroll
    for (int kk = 0; kk < 4; kk++)
      af[m][kk] = *(const short8*)&sA[w][arow][m * 128 + kk * 32 + kgrp];

  const short8* F = (const short8*)frags;
#pragma unroll
  for (int nt = 0; nt < 8; ++nt) {
    f32x4 c_ns = {0,0,0,0}, c_su = {0,0,0,0};
    f32x4 c_vx = {0,0,0,0}, c_vy = {0,0,0,0}, c_vz = {0,0,0,0};
#pragma unroll
    for (int kk = 0; kk < 4; ++kk) {
      c_ns = __builtin_amdgcn_mfma_f32_16x16x32_bf16(af[0][kk], F[(116 + (0 * 4 + kk) * 8 + nt) * 64 + lane], c_ns, 0, 0, 0);
      c_su = __builtin_amdgcn_mfma_f32_16x16x32_bf16(af[0][kk], F[(116 + (1 * 4 + kk) * 8 + nt) * 64 + lane], c_su, 0, 0, 0);
      c_vx = __builtin_amdgcn_mfma_f32_16x16x32_bf16(af[1][kk], F[(116 + (2 * 4 + kk) * 8 + nt) * 64 + lane], c_vx, 0, 0, 0);
      c_vy = __builtin_amdgcn_mfma_f32_16x16x32_bf16(af[2][kk], F[(116 + (2 * 4 + kk) * 8 + nt) * 64 + lane], c_vy, 0, 0, 0);
      c_vz = __builtin_amdgcn_mfma_f32_16x16x32_bf16(af[3][kk], F[(116 + (2 * 4 + kk) * 8 + nt) * 64 + lane], c_vz, 0, 0, 0);
    }
    const int col = nt * 16 + (lane & 15);
#pragma unroll
    for (int rr = 0; rr < 4; ++rr) {
      int nd = nbase + ((lane >> 4) << 2) + rr;
      if (nd < N) {
        ns_bf[(size_t)nd * 128 + col] = f2bf(c_ns[rr]);
        short4v p;
        p[0] = f2bf(c_su[rr]); p[1] = f2bf(c_vx[rr]);
        p[2] = f2bf(c_vy[rr]); p[3] = f2bf(c_vz[rr]);
        suvu[(size_t)nd * 128 + col] = p;
      }
    }
  }
}

// ---------------------------------------------------------------- sort kernels
__global__ __launch_bounds__(1024)
void scan_kernel(const int* __restrict__ cnt, int* __restrict__ rs,
                 int* __restrict__ cursor, int N)
{
  __shared__ int wsum[16];
  __shared__ int carry_s;
  const int tid = threadIdx.x, lane = tid & 63, wid = tid >> 6;
  if (tid == 0) { carry_s = 0; rs[0] = 0; }
  __syncthreads();
  for (int base = 0; base < N; base += 1024) {
    int i = base + tid;
    int v = (i < N) ? cnt[i] : 0;
    int x = v;
#pragma unroll
    for (int off = 1; off < 64; off <<= 1) {
      int t = __shfl_up(x, off);
      if (lane >= off) x += t;
    }
    if (lane == 63) wsum[wid] = x;
    __syncthreads();
    if (tid == 0) {
      int acc = carry_s;
#pragma unroll
      for (int k = 0; k < 16; k++) { int t = wsum[k]; wsum[k] = acc; acc += t; }
      carry_s = acc;
    }
    __syncthreads();
    int inc = x + wsum[wid];
    if (i < N) { rs[i + 1] = inc; cursor[i] = inc - v; }
    __syncthreads();
  }
}

__global__ __launch_bounds__(256)
void scatter_kernel(const int* __restrict__ eidx, int* __restrict__ cursor,
                    int* __restrict__ perm, int E)
{
  int e = blockIdx.x * 256 + threadIdx.x;
  if (e < E) {
    int r = eidx[E + e];
    int pos = atomicAdd(&cursor[r], 1);
    perm[pos] = e;
  }
}

// ---------------------------------------------------------------- edge MLP v4
#define EB 32   // edges per block (2 waves x 16)

__global__ __launch_bounds__(128, 4)
void edge_mlp(const float* __restrict__ elen,
              const float* __restrict__ tdif,
              const float* __restrict__ lens,
              const int*   __restrict__ eidx,
              const float4* __restrict__ nrm_c,
              const short* __restrict__ ns_bf,
              const short* __restrict__ frags,
              const int*   __restrict__ perm,
              short* __restrict__ tpw,
              int e_lo, int E)
{
  __shared__ __align__(16) float smu[288], sva[288], sw_[288], sb_[288];
  __shared__ __align__(16) short hA[EB][72];
  __shared__ __align__(16) short hB[EB][72];

  const int tid  = threadIdx.x;
  const int lane = tid & 63;
  const int w    = tid >> 6;

  // ---- stage norm table as scalar arrays (k>=265: w=0 kills value) ----
  for (int i = tid; i < 288; i += 128) {
    float4 c;
    if (i < 265) c = nrm_c[i];
    else { c.x = 0.f; c.y = 1.f; c.z = 0.f; c.w = 0.f; }
    smu[i] = c.x; sva[i] = c.y; sw_[i] = c.z; sb_[i] = c.w;
  }
  const float4 mix = nrm_c[265];          // {msm0, vsm0, -, -}
  const float msm0 = mix.x, vsm0 = mix.y;

  // ---- per-lane edge meta (redundant across the 4 lane-groups) ----
  const int e16 = lane & 15, grp = lane >> 4;
  int gi = e_lo + blockIdx.x * EB + w * 16 + e16;
  if (gi >= E) gi = E - 1;
  const int e = perm[gi];
  const int snd = eidx[e], rcv = eidx[E + e];
  const float r = elen[e], tt = tdif[e];
  float uu_ = r * 0.2f;
  float u2 = uu_ * uu_, u4 = u2 * u2, u5 = u4 * uu_;
  float cc = 1.0f - 21.0f * u5 + 35.0f * u5 * uu_ - 15.0f * u5 * u2;
  const float cut = (uu_ < 1.0f) ? cc : 0.0f;
  const float lncut = lens[e] * cut;

  // ---- build raw A-fragments: plain bf16 loads; stats from g*cut in fp32 ----
  short8 raw[9];
  float s1 = 0.f, s2 = 0.f;
#pragma unroll
  for (int kk = 0; kk < 8; ++kk) {
    const size_t rowb = (kk < 4) ? (size_t)snd * 128 + kk * 32
                                 : (size_t)rcv * 128 + (kk - 4) * 32;
    raw[kk] = *(const short8*)&ns_bf[rowb + grp * 8];
#pragma unroll
    for (int i = 0; i < 8; i++) {
      float v = bf2f(raw[kk][i]) * cut;
      s1 += v; s2 += v * v;
    }
  }
  {
    float v[8];
    if (grp == 0) {
      const float pref = sqrtf(0.4f);
#pragma unroll
      for (int i = 0; i < 8; i++) {
        float kn = (float)(i + 1) * (PI_F / 5.0f);
        v[i] = pref * __sinf(kn * r) / r * __expf(-kn * kn * tt) * cut;
      }
    } else if (grp == 1) {
      v[0] = lncut;
#pragma unroll
      for (int i = 1; i < 8; i++) v[i] = 0.f;
    } else {
#pragma unroll
      for (int i = 0; i < 8; i++) v[i] = 0.f;
    }
#pragma unroll
    for (int i = 0; i < 8; i++) {
      s1 += v[i]; s2 += v[i] * v[i];
      raw[8][i] = f2bf(v[i]);
    }
  }
  // stats reduce across lane-groups {l, l^16, l^32, l^48}
  s1 += __shfl_xor(s1, 16); s1 += __shfl_xor(s1, 32);
  s2 += __shfl_xor(s2, 16); s2 += __shfl_xor(s2, 32);
  const float mean = s1 * (1.0f / 265.0f);
  const float var  = (s2 - s1 * mean) * (1.0f / 264.0f);   // ddof=1
  const float mupart = msm0 * mean;
  const float vapart = vsm0 * var;

  __syncthreads();   // norm tables staged

  // ======== MFMA layers ========
  const short8* F = (const short8*)frags;
  const int arow = w * 16 + (lane & 15);
  const int kgrp = (lane >> 4) << 3;

  // ---- layer 1: 288 -> 64, normalize fused per-kk; cut folded into affine ----
  f32x4 A0 = {0,0,0,0}, A1 = {0,0,0,0}, A2 = {0,0,0,0}, A3 = {0,0,0,0};
#pragma unroll
  for (int kk = 0; kk < 9; ++kk) {
    const int k0 = kk * 32 + grp * 8;
    const float cfac = (kk < 8) ? cut : 1.0f;   // raw[8] already carries cut
    short8 a;
#pragma unroll
    for (int h = 0; h < 2; ++h) {
      float4 mu4 = *(const float4*)&smu[k0 + 4 * h];
      float4 va4 = *(const float4*)&sva[k0 + 4 * h];
      float4 w4  = *(const float4*)&sw_[k0 + 4 * h];
      float4 b4  = *(const float4*)&sb_[k0 + 4 * h];
#pragma unroll
      for (int i = 0; i < 4; ++i) {
        float va = vapart + ((const float*)&va4)[i];
        float t  = __builtin_amdgcn_rsq(va) * ((const float*)&w4)[i];
        float mb = fmaf(-(mupart + ((const float*)&mu4)[i]), t, ((const float*)&b4)[i]);
        a[4 * h + i] = f2bf(fmaf(bf2f(raw[kk][4 * h + i]), cfac * t, mb));
      }
    }
    A0 = __builtin_amdgcn_mfma_f32_16x16x32_bf16(a, F[(kk * 4 + 0) * 64 + lane], A0, 0, 0, 0);
    A1 = __builtin_amdgcn_mfma_f32_16x16x32_bf16(a, F[(kk * 4 + 1) * 64 + lane], A1, 0, 0, 0);
    A2 = __builtin_amdgcn_mfma_f32_16x16x32_bf16(a, F[(kk * 4 + 2) * 64 + lane], A2, 0, 0, 0);
    A3 = __builtin_amdgcn_mfma_f32_16x16x32_bf16(a, F[(kk * 4 + 3) * 64 + lane], A3, 0, 0, 0);
  }
#pragma unroll
  for (int rr = 0; rr < 4; ++rr) {
    int er = w * 16 + ((lane >> 4) << 2) + rr;
    hA[er][ 0 + (lane & 15)] = f2bf(silu_f(A0[rr]));
    hA[er][16 + (lane & 15)] = f2bf(silu_f(A1[rr]));
    hA[er][32 + (lane & 15)] = f2bf(silu_f(A2[rr]));
    hA[er][48 + (lane & 15)] = f2bf(silu_f(A3[rr]));
  }
  __syncthreads();

  // ---- layer 2: 64 -> 64 ----
  A0 = A1 = A2 = A3 = (f32x4){0,0,0,0};
#pragma unroll
  for (int kk = 0; kk < 2; ++kk) {
    short8 a = *(const short8*)&hA[arow][kk * 32 + kgrp];
    A0 = __builtin_amdgcn_mfma_f32_16x16x32_bf16(a, F[(36 + kk * 4 + 0) * 64 + lane], A0, 0, 0, 0);
    A1 = __builtin_amdgcn_mfma_f32_16x16x32_bf16(a, F[(36 + kk * 4 + 1) * 64 + lane], A1, 0, 0, 0);
    A2 = __builtin_amdgcn_mfma_f32_16x16x32_bf16(a, F[(36 + kk * 4 + 2) * 64 + lane], A2, 0, 0, 0);
    A3 = __builtin_amdgcn_mfma_f32_16x16x32_bf16(a, F[(36 + kk * 4 + 3) * 64 + lane], A3, 0, 0, 0);
  }
#pragma unroll
  for (int rr = 0; rr < 4; ++rr) {
    int er = w * 16 + ((lane >> 4) << 2) + rr;
    hB[er][ 0 + (lane & 15)] = f2bf(silu_f(A0[rr]));
    hB[er][16 + (lane & 15)] = f2bf(silu_f(A1[rr]));
    hB[er][32 + (lane & 15)] = f2bf(silu_f(A2[rr]));
    hB[er][48 + (lane & 15)] = f2bf(silu_f(A3[rr]));
  }
  __syncthreads();

  // ---- layer 3: 64 -> 64 ----
  A0 = A1 = A2 = A3 = (f32x4){0,0,0,0};
#pragma unroll
  for (int kk = 0; kk < 2; ++kk) {
    short8 a = *(const short8*)&hB[arow][kk * 32 + kgrp];
    A0 = __builtin_amdgcn_mfma_f32_16x16x32_bf16(a, F[(44 + kk * 4 + 0) * 64 + lane], A0, 0, 0, 0);
    A1 = __builtin_amdgcn_mfma_f32_16x16x32_bf16(a, F[(44 + kk * 4 + 1) * 64 + lane], A1, 0, 0, 0);
    A2 = __builtin_amdgcn_mfma_f32_16x16x32_bf16(a, F[(44 + kk * 4 + 2) * 64 + lane], A2, 0, 0, 0);
    A3 = __builtin_amdgcn_mfma_f32_16x16x32_bf16(a, F[(44 + kk * 4 + 3) * 64 + lane], A3, 0, 0, 0);
  }
  __syncthreads();
#pragma unroll
  for (int rr = 0; rr < 4; ++rr) {
    int er = w * 16 + ((lane >> 4) << 2) + rr;
    hA[er][ 0 + (lane & 15)] = f2bf(silu_f(A0[rr]));
    hA[er][16 + (lane & 15)] = f2bf(silu_f(A1[rr]));
    hA[er][32 + (lane & 15)] = f2bf(silu_f(A2[rr]));
    hA[er][48 + (lane & 15)] = f2bf(silu_f(A3[rr]));
  }
  __syncthreads();

  short8 a40 = *(const short8*)&hA[arow][ 0 + kgrp];
  short8 a41 = *(const short8*)&hA[arow][32 + kgrp];
  const int rowbase = blockIdx.x * EB + w * 16 + ((lane >> 4) << 2);

  // ---- layer 4: 64 -> 512, write tpw (col-packed w0,w1,w2,w3) ----
#pragma unroll
  for (int t = 0; t < 8; ++t) {
    f32x4 W0 = {0,0,0,0}, W1t = {0,0,0,0}, W2t = {0,0,0,0}, W3t = {0,0,0,0};
    W0  = __builtin_amdgcn_mfma_f32_16x16x32_bf16(a40, F[(52 + 0 * 32 + ( 0 + t)) * 64 + lane], W0,  0, 0, 0);
    W0  = __builtin_amdgcn_mfma_f32_16x16x32_bf16(a41, F[(52 + 1 * 32 + ( 0 + t)) * 64 + lane], W0,  0, 0, 0);
    W1t = __builtin_amdgcn_mfma_f32_16x16x32_bf16(a40, F[(52 + 0 * 32 + ( 8 + t)) * 64 + lane], W1t, 0, 0, 0);
    W1t = __builtin_amdgcn_mfma_f32_16x16x32_bf16(a41, F[(52 + 1 * 32 + ( 8 + t)) * 64 + lane], W1t, 0, 0, 0);
    W2t = __builtin_amdgcn_mfma_f32_16x16x32_bf16(a40, F[(52 + 0 * 32 + (16 + t)) * 64 + lane], W2t, 0, 0, 0);
    W2t = __builtin_amdgcn_mfma_f32_16x16x32_bf16(a41, F[(52 + 1 * 32 + (16 + t)) * 64 + lane], W2t, 0, 0, 0);
    W3t = __builtin_amdgcn_mfma_f32_16x16x32_bf16(a40, F[(52 + 0 * 32 + (24 + t)) * 64 + lane], W3t, 0, 0, 0);
    W3t = __builtin_amdgcn_mfma_f32_16x16x32_bf16(a41, F[(52 + 1 * 32 + (24 + t)) * 64 + lane], W3t, 0, 0, 0);

    const int uu = t * 16 + (lane & 15);
#pragma unroll
    for (int rr = 0; rr < 4; ++rr) {
      short4v pk;
      pk[0] = f2bf(W0[rr]); pk[1] = f2bf(W1t[rr]);
      pk[2] = f2bf(W2t[rr]); pk[3] = f2bf(W3t[rr]);
      *(short4v*)(tpw + (size_t)(rowbase + rr) * 512 + uu * 4) = pk;
    }
  }
}

// ---------------------------------------------------------------- gather kernel
// 2 blocks per node (column halves), 64 threads each; pipelined inner loop;
// bf16 M output (out_mfma consumes bf16 anyway).
__global__ __launch_bounds__(64)
void gather_kernel(const int* __restrict__ rs, const int* __restrict__ perm,
                   const int* __restrict__ eidx, const float* __restrict__ eattr,
                   const short4v* __restrict__ suvu,
                   const short* __restrict__ tpw,
                   short* __restrict__ M0b, short* __restrict__ M1b,
                   int e_lo, int e_hi, int E, int writemode)
{
  __shared__ int   s_snd[64];
  __shared__ __align__(16) float s_y[64][4];

  const int n    = blockIdx.x >> 1;
  const int half = blockIdx.x & 1;
  const int tid  = threadIdx.x;
  const int o    = half * 64 + tid;        // column 0..127
  int lo = rs[n], hi = rs[n + 1];
  if (lo < e_lo) lo = e_lo;
  if (hi > e_hi) hi = e_hi;
  if (!writemode && lo >= hi) return;

  float a0 = 0.f, a1 = 0.f;
  float b0 = 0.f, b1 = 0.f, b2 = 0.f;
  float c0 = 0.f, c1 = 0.f, c2 = 0.f;

  for (int base = lo; base < hi; base += 64) {
    const int cnt_ = min(64, hi - base);
    __syncthreads();
    if (tid < cnt_) {
      int e = perm[base + tid];
      s_snd[tid] = eidx[e];
      *(float4*)&s_y[tid][0] = *(const float4*)&eattr[e * 4];
    }
    __syncthreads();
    // software pipeline: prefetch j+1 while computing j
    short4v sv = suvu[(size_t)s_snd[0] * 128 + o];
    short4v pk = *(const short4v*)(tpw + (size_t)(base - e_lo) * 512 + o * 4);
    for (int j = 0; j < cnt_; ++j) {
      short4v sv_n = sv, pk_n = pk;
      if (j + 1 < cnt_) {
        sv_n = suvu[(size_t)s_snd[j + 1] * 128 + o];
        pk_n = *(const short4v*)(tpw + (size_t)(base + j + 1 - e_lo) * 512 + o * 4);
      }
      const float4 y = *(const float4*)&s_y[j][0];
      const float se = bf2f(sv[0]);
      const float v0 = bf2f(sv[1]);
      const float v1 = bf2f(sv[2]);
      const float v2 = bf2f(sv[3]);
      const float w0 = bf2f(pk[0]), w1 = bf2f(pk[1]);
      const float w2 = bf2f(pk[2]), w3 = bf2f(pk[3]);
      const float dot = v0 * y.y + v1 * y.z + v2 * y.w;
      a0 = fmaf(w0 * se, y.x, a0);
      a1 = fmaf(w3, dot, a1);                        // isq3 folded into w3
      const float s1v = w1 * se;
      b0 = fmaf(s1v, y.y, b0); b1 = fmaf(s1v, y.z, b1); b2 = fmaf(s1v, y.w, b2);
      const float vv = w2 * y.x;
      c0 = fmaf(vv, v0, c0); c1 = fmaf(vv, v1, c1); c2 = fmaf(vv, v2, c2);
      sv = sv_n; pk = pk_n;
    }
  }
  short* p0 = M0b + (size_t)n * 256;
  short* p1 = M1b + (size_t)n * 768;
  if (writemode) {
    p0[o] = f2bf(a0); p0[128 + o] = f2bf(a1);
    p1[0 * 256 + o] = f2bf(b0); p1[1 * 256 + o] = f2bf(b1); p1[2 * 256 + o] = f2bf(b2);
    p1[0 * 256 + 128 + o] = f2bf(c0); p1[1 * 256 + 128 + o] = f2bf(c1); p1[2 * 256 + 128 + o] = f2bf(c2);
  } else {
    p0[o] = f2bf(bf2f(p0[o]) + a0); p0[128 + o] = f2bf(bf2f(p0[128 + o]) + a1);
    p1[0 * 256 + o] = f2bf(bf2f(p1[0 * 256 + o]) + b0);
    p1[1 * 256 + o] = f2bf(bf2f(p1[1 * 256 + o]) + b1);
    p1[2 * 256 + o] = f2bf(bf2f(p1[2 * 256 + o]) + b2);
    p1[0 * 256 + 128 + o] = f2bf(bf2f(p1[0 * 256 + 128 + o]) + c0);
    p1[1 * 256 + 128 + o] = f2bf(bf2f(p1[1 * 256 + 128 + o]) + c1);
    p1[2 * 256 + 128 + o] = f2bf(bf2f(p1[2 * 256 + 128 + o]) + c2);
  }
}

// ---------------------------------------------------------------- out MFMA
__global__ __launch_bounds__(128)
void out_mfma(const short* __restrict__ M0b, const short* __restrict__ M1b,
              const short* __restrict__ frags, float* __restrict__ out, int N)
{
  const int tid = threadIdx.x, lane = tid & 63, w = tid >> 6;
  const int nbase = blockIdx.x * 32 + w * 16;
  const int kgrp = (lane >> 4) << 3;
  int nd = nbase + (lane & 15); if (nd >= N) nd = N - 1;

  const short* rowp[4];
  rowp[0] = M0b + (size_t)nd * 256;
  rowp[1] = M1b + (size_t)nd * 768;
  rowp[2] = M1b + (size_t)nd * 768 + 256;
  rowp[3] = M1b + (size_t)nd * 768 + 512;

  f32x4 acc[8][4];
#pragma unroll
  for (int nt = 0; nt < 8; ++nt)
#pragma unroll
    for (int s = 0; s < 4; ++s) acc[nt][s] = (f32x4){0,0,0,0};

  const short8* F = (const short8*)frags;
#pragma unroll
  for (int kc = 0; kc < 8; ++kc) {
    short8 a[4];
#pragma unroll
    for (int s = 0; s < 4; ++s)
      a[s] = *(const short8*)&rowp[s][kc * 32 + kgrp];
#pragma unroll
    for (int nt = 0; nt < 8; ++nt) {
      short8 b0 = F[(212 + kc * 8 + nt) * 64 + lane];
      short8 b1 = F[(276 + kc * 8 + nt) * 64 + lane];
      acc[nt][0] = __builtin_amdgcn_mfma_f32_16x16x32_bf16(a[0], b0, acc[nt][0], 0, 0, 0);
      acc[nt][1] = __builtin_amdgcn_mfma_f32_16x16x32_bf16(a[1], b1, acc[nt][1], 0, 0, 0);
      acc[nt][2] = __builtin_amdgcn_mfma_f32_16x16x32_bf16(a[2], b1, acc[nt][2], 0, 0, 0);
      acc[nt][3] = __builtin_amdgcn_mfma_f32_16x16x32_bf16(a[3], b1, acc[nt][3], 0, 0, 0);
    }
  }

#pragma unroll
  for (int nt = 0; nt < 8; ++nt) {
    const int col = nt * 16 + (lane & 15);
#pragma unroll
    for (int rr = 0; rr < 4; ++rr) {
      int n = nbase + ((lane >> 4) << 2) + rr;
      if (n < N) {
        float4 r;
        r.x = acc[nt][0][rr];
        r.y = acc[nt][1][rr];
        r.z = acc[nt][2][rr];
        r.w = acc[nt][3][rr];
        *(float4*)(out + ((size_t)n * 128 + col) * 4) = r;
      }
    }
  }
}

// ---------------------------------------------------------------- launcher
extern "C" void kernel_launch(void* const* d_in, const int* in_sizes, int n_in,
                              void* d_out, int out_size, void* d_ws, size_t ws_size,
                              hipStream_t stream)
{
  const float* nf   = (const float*)d_in[0];
  const float* eattr= (const float*)d_in[1];
  const float* elen = (const float*)d_in[2];
  const float* tdif = (const float*)d_in[3];
  const float* lens = (const float*)d_in[4];
  const int*   eidx = (const int*)  d_in[5];
  const float* Wsc  = (const float*)d_in[6];
  const float* Wu0  = (const float*)d_in[7];
  const float* Wu1  = (const float*)d_in[8];
  const float* snw  = (const float*)d_in[9];
  const float* snb  = (const float*)d_in[10];
  const float* snmw = (const float*)d_in[11];
  const float* snvw = (const float*)d_in[12];
  const float* snrm = (const float*)d_in[13];
  const float* snrv = (const float*)d_in[14];
  const float* W1   = (const float*)d_in[15];
  const float* W2   = (const float*)d_in[16];
  const float* W3   = (const float*)d_in[17];
  const float* W4   = (const float*)d_in[18];
  const float* Wo0  = (const float*)d_in[19];
  const float* Wo1  = (const float*)d_in[20];

  const int N = in_sizes[0] / 512;
  const int E = in_sizes[1] / 4;

  char* p = (char*)d_ws;
  short*   ns_bf = (short*)p;    p += (size_t)N * 128 * 2;
  short4v* suvu  = (short4v*)p;  p += (size_t)N * 128 * 8;
  short*   M0b   = (short*)p;    p += (size_t)N * 256 * 2;
  short*   M1b   = (short*)p;    p += (size_t)N * 768 * 2;
  float4*  nrm_c = (float4*)p;   p += 266 * 16;
  short*   frags = (short*)p;    p += (size_t)340 * 64 * 8 * 2;
  int* cnt    = (int*)p;         p += (size_t)N * 4;
  int* rs     = (int*)p;         p += (size_t)(N + 1) * 4;
  int* cursor = (int*)p;         p += (size_t)N * 4;
  int* perm   = (int*)p;         p += (size_t)E * 4;
  size_t used = (size_t)(p - (char*)d_ws);
  used = (used + 255) & ~(size_t)255;
  short* tpw = (short*)((char*)d_ws + used);
  size_t avail = (ws_size > used) ? (ws_size - used) : 0;

  long long chunk = (long long)(avail / 1024) & ~31LL;   // edges per chunk (1KB each)
  long long Eup = ((long long)E + 31) & ~31LL;
  if (chunk > Eup) chunk = Eup;
  if (chunk < 32)  chunk = 32;            // last-resort (assumes ws covers it)
  const int writemode = (chunk >= Eup) ? 1 : 0;

  if (!writemode)
    hipMemsetAsync(M0b, 0, (size_t)1024 * N * sizeof(short), stream);
  hipMemsetAsync(cnt, 0, (size_t)N * sizeof(int), stream);

  const int hist_blocks = (E + 255) / 256;
  prep_fused<<<dim3(87 + hist_blocks), dim3(256), 0, stream>>>(
      W1, W2, W3, W4, Wsc, Wu0, Wu1, Wo0, Wo1,
      snw, snb, snmw, snvw, snrm, snrv, eidx, frags, nrm_c, cnt, E);
  node_mfma<<<dim3((N + 31) / 32), dim3(128), 0, stream>>>(nf, frags, ns_bf, suvu, N);
  scan_kernel<<<dim3(1), dim3(1024), 0, stream>>>(cnt, rs, cursor, N);
  scatter_kernel<<<dim3((E + 255) / 256), dim3(256), 0, stream>>>(eidx, cursor, perm, E);

  for (long long lo = 0; lo < E; lo += chunk) {
    int n_e = (int)(((long long)E - lo < chunk) ? ((long long)E - lo) : chunk);
    int blocks = (n_e + EB - 1) / EB;
    edge_mlp<<<dim3(blocks), dim3(128), 0, stream>>>(
        elen, tdif, lens, eidx, nrm_c, ns_bf, frags, perm, tpw, (int)lo, E);
    gather_kernel<<<dim3(2 * N), dim3(64), 0, stream>>>(
        rs, perm, eidx, eattr, suvu, tpw, M0b, M1b, (int)lo, (int)(lo + n_e), E, writemode);
  }

  out_mfma<<<dim3((N + 31) / 32), dim3(128), 0, stream>>>(M0b, M1b, frags, (float*)d_out, N);
}

// Round 15
// 216.949 us; speedup vs baseline: 1.0158x; 1.0158x over previous
//
#include <hip/hip_runtime.h>
#include <hip/hip_bf16.h>
#include <math.h>

// Round 15: restore round-13 exactly (best measured: 217.3 µs).
//   Structure: prep_fused -> node_mfma -> scan/scatter (CSR by receiver) ->
//   edge_mlp (reg-resident wi, fused normalize, MFMA MLP, tpw bf16) ->
//   gather (2 col-half blocks/node, pipelined) -> out_mfma.

#define PI_F 3.14159265358979323846f

typedef short  short8 __attribute__((ext_vector_type(8)));
typedef short  short4v __attribute__((ext_vector_type(4)));
typedef float  f32x4 __attribute__((ext_vector_type(4)));

static __device__ __forceinline__ float silu_f(float x) {
  return x / (1.0f + __expf(-x));
}
static __device__ __forceinline__ short f2bf(float x) {
  __hip_bfloat16 h = __float2bfloat16(x);
  return *reinterpret_cast<short*>(&h);
}
static __device__ __forceinline__ float bf2f(short s) {
  __hip_bfloat16 h = *reinterpret_cast<__hip_bfloat16*>(&s);
  return __bfloat162float(h);
}

// ---------------------------------------------------------------- prep fused
// blocks [0,85): weight frags | [85,87): norm table | [87,..): receiver hist
__global__ __launch_bounds__(256)
void prep_fused(const float* __restrict__ W1, const float* __restrict__ W2,
                const float* __restrict__ W3, const float* __restrict__ W4,
                const float* __restrict__ Wsc, const float* __restrict__ Wu0,
                const float* __restrict__ Wu1,
                const float* __restrict__ Wo0, const float* __restrict__ Wo1,
                const float* __restrict__ snw, const float* __restrict__ snb,
                const float* __restrict__ snmw, const float* __restrict__ snvw,
                const float* __restrict__ snrm, const float* __restrict__ snrv,
                const int* __restrict__ eidx,
                short* __restrict__ frags, float4* __restrict__ nrm_c,
                int* __restrict__ cnt, int E)
{
  const int b = blockIdx.x;
  if (b < 85) {
    int t = b * 256 + threadIdx.x;
    if (t >= 340 * 64) return;
    int frag = t >> 6, lane = t & 63;
    const float* W; int K, Nout, kk, nt; float scale;
    if (frag < 36)       { int f = frag;       W = W1; K = 265; Nout = 64;  kk = f >> 2; nt = f & 3;  scale = 1.0f / sqrtf(265.0f); }
    else if (frag < 44)  { int f = frag - 36;  W = W2; K = 64;  Nout = 64;  kk = f >> 2; nt = f & 3;  scale = 0.125f; }
    else if (frag < 52)  { int f = frag - 44;  W = W3; K = 64;  Nout = 64;  kk = f >> 2; nt = f & 3;  scale = 0.125f; }
    else if (frag < 116) { int f = frag - 52;  W = W4; K = 64;  Nout = 512; kk = f >> 5; nt = f & 31;
                           scale = 0.125f * ((nt >= 24) ? 0.57735026918962576f : 1.0f); }
    else if (frag < 212) { int f = frag - 116; int m = f >> 5; kk = (f >> 3) & 3; nt = f & 7;
                           W = (m == 0) ? Wsc : ((m == 1) ? Wu0 : Wu1);
                           K = 128; Nout = 128; scale = 0.088388347648318447f; }
    else if (frag < 276) { int f = frag - 212; W = Wo0; K = 256; Nout = 128; kk = f >> 3; nt = f & 7;
                           scale = 1.0f / 256.0f; }
    else                 { int f = frag - 276; W = Wo1; K = 256; Nout = 128; kk = f >> 3; nt = f & 7;
                           scale = 1.0f / 256.0f; }
    int n = nt * 16 + (lane & 15);
    short* out = frags + ((size_t)(frag * 64 + lane)) * 8;
#pragma unroll
    for (int i = 0; i < 8; i++) {
      int k = kk * 32 + ((lane >> 4) << 3) + i;
      float v = (k < K) ? W[(size_t)k * Nout + n] * scale : 0.0f;
      out[i] = f2bf(v);
    }
  } else if (b < 87) {
    int k = (b - 85) * 256 + threadIdx.x;
    float msm0 = 1.0f / (1.0f + __expf(snmw[1] - snmw[0]));
    float vsm0 = 1.0f / (1.0f + __expf(snvw[1] - snvw[0]));
    if (k < 265) {
      float4 c;
      c.x = (1.0f - msm0) * snrm[k];
      c.y = (1.0f - vsm0) * snrv[k] + 1e-5f;
      c.z = snw[k];
      c.w = snb[k];
      nrm_c[k] = c;
    } else if (k == 265) {
      float4 c; c.x = msm0; c.y = vsm0; c.z = 0.f; c.w = 0.f;
      nrm_c[k] = c;
    }
  } else {
    int e = (b - 87) * 256 + threadIdx.x;
    if (e < E) atomicAdd(&cnt[eidx[E + e]], 1);
  }
}

// ---------------------------------------------------------------- node MFMA
#define NPW 16
__global__ __launch_bounds__(128)
void node_mfma(const float* __restrict__ nf, const short* __restrict__ frags,
               short* __restrict__ ns_bf, short4v* __restrict__ suvu, int N)
{
  __shared__ __align__(16) short sA[2][16][520];   // [wave][node][s|vx|vy|vz], +8 pad

  const int tid = threadIdx.x, lane = tid & 63, w = tid >> 6;
  const int nbase = blockIdx.x * (2 * NPW) + w * NPW;

  for (int it = 0; it < 32; ++it) {
    int idx = it * 64 + lane;
    int nd  = idx >> 7;
    int c4  = (idx & 127) << 2;
    int gn  = nbase + nd; if (gn >= N) gn = N - 1;
    float4 g = *(const float4*)&nf[(size_t)gn * 512 + c4];
#pragma unroll
    for (int i = 0; i < 4; i++) {
      int c = c4 + i;
      int pos;
      if (c < 128) pos = c;
      else { int j = c - 128; int u = j / 3, d = j - 3 * u; pos = 128 + (d << 7) + u; }
      sA[w][nd][pos] = f2bf(((const float*)&g)[i]);
    }
  }
  __syncthreads();

  const int arow = lane & 15;
  const int kgrp = (lane >> 4) << 3;
  short8 af[4][4];
#pragma unroll
  for (int m = 0; m < 4; m++)
#pragma unroll
    for (int kk = 0; kk < 4; kk++)
      af[m][kk] = *(const short8*)&sA[w][arow][m * 128 + kk * 32 + kgrp];

  const short8* F = (const short8*)frags;
#pragma unroll
  for (int nt = 0; nt < 8; ++nt) {
    f32x4 c_ns = {0,0,0,0}, c_su = {0,0,0,0};
    f32x4 c_vx = {0,0,0,0}, c_vy = {0,0,0,0}, c_vz = {0,0,0,0};
#pragma unroll
    for (int kk = 0; kk < 4; ++kk) {
      c_ns = __builtin_amdgcn_mfma_f32_16x16x32_bf16(af[0][kk], F[(116 + (0 * 4 + kk) * 8 + nt) * 64 + lane], c_ns, 0, 0, 0);
      c_su = __builtin_amdgcn_mfma_f32_16x16x32_bf16(af[0][kk], F[(116 + (1 * 4 + kk) * 8 + nt) * 64 + lane], c_su, 0, 0, 0);
      c_vx = __builtin_amdgcn_mfma_f32_16x16x32_bf16(af[1][kk], F[(116 + (2 * 4 + kk) * 8 + nt) * 64 + lane], c_vx, 0, 0, 0);
      c_vy = __builtin_amdgcn_mfma_f32_16x16x32_bf16(af[2][kk], F[(116 + (2 * 4 + kk) * 8 + nt) * 64 + lane], c_vy, 0, 0, 0);
      c_vz = __builtin_amdgcn_mfma_f32_16x16x32_bf16(af[3][kk], F[(116 + (2 * 4 + kk) * 8 + nt) * 64 + lane], c_vz, 0, 0, 0);
    }
    const int col = nt * 16 + (lane & 15);
#pragma unroll
    for (int rr = 0; rr < 4; ++rr) {
      int nd = nbase + ((lane >> 4) << 2) + rr;
      if (nd < N) {
        ns_bf[(size_t)nd * 128 + col] = f2bf(c_ns[rr]);
        short4v p;
        p[0] = f2bf(c_su[rr]); p[1] = f2bf(c_vx[rr]);
        p[2] = f2bf(c_vy[rr]); p[3] = f2bf(c_vz[rr]);
        suvu[(size_t)nd * 128 + col] = p;
      }
    }
  }
}

// ---------------------------------------------------------------- sort kernels
__global__ __launch_bounds__(1024)
void scan_kernel(const int* __restrict__ cnt, int* __restrict__ rs,
                 int* __restrict__ cursor, int N)
{
  __shared__ int wsum[16];
  __shared__ int carry_s;
  const int tid = threadIdx.x, lane = tid & 63, wid = tid >> 6;
  if (tid == 0) { carry_s = 0; rs[0] = 0; }
  __syncthreads();
  for (int base = 0; base < N; base += 1024) {
    int i = base + tid;
    int v = (i < N) ? cnt[i] : 0;
    int x = v;
#pragma unroll
    for (int off = 1; off < 64; off <<= 1) {
      int t = __shfl_up(x, off);
      if (lane >= off) x += t;
    }
    if (lane == 63) wsum[wid] = x;
    __syncthreads();
    if (tid == 0) {
      int acc = carry_s;
#pragma unroll
      for (int k = 0; k < 16; k++) { int t = wsum[k]; wsum[k] = acc; acc += t; }
      carry_s = acc;
    }
    __syncthreads();
    int inc = x + wsum[wid];
    if (i < N) { rs[i + 1] = inc; cursor[i] = inc - v; }
    __syncthreads();
  }
}

__global__ __launch_bounds__(256)
void scatter_kernel(const int* __restrict__ eidx, int* __restrict__ cursor,
                    int* __restrict__ perm, int E)
{
  int e = blockIdx.x * 256 + threadIdx.x;
  if (e < E) {
    int r = eidx[E + e];
    int pos = atomicAdd(&cursor[r], 1);
    perm[pos] = e;
  }
}

// ---------------------------------------------------------------- edge MLP v3
#define EB 32   // edges per block (2 waves x 16)

__global__ __launch_bounds__(128, 4)
void edge_mlp(const float* __restrict__ elen,
              const float* __restrict__ tdif,
              const float* __restrict__ lens,
              const int*   __restrict__ eidx,
              const float4* __restrict__ nrm_c,
              const short* __restrict__ ns_bf,
              const short* __restrict__ frags,
              const int*   __restrict__ perm,
              short* __restrict__ tpw,
              int e_lo, int E)
{
  __shared__ __align__(16) float smu[288], sva[288], sw_[288], sb_[288];
  __shared__ __align__(16) short hA[EB][72];
  __shared__ __align__(16) short hB[EB][72];

  const int tid  = threadIdx.x;
  const int lane = tid & 63;
  const int w    = tid >> 6;

  // ---- stage norm table as scalar arrays (k>=265: w=0 kills value) ----
  for (int i = tid; i < 288; i += 128) {
    float4 c;
    if (i < 265) c = nrm_c[i];
    else { c.x = 0.f; c.y = 1.f; c.z = 0.f; c.w = 0.f; }
    smu[i] = c.x; sva[i] = c.y; sw_[i] = c.z; sb_[i] = c.w;
  }
  const float4 mix = nrm_c[265];          // {msm0, vsm0, -, -}
  const float msm0 = mix.x, vsm0 = mix.y;

  // ---- per-lane edge meta (redundant across the 4 lane-groups) ----
  const int e16 = lane & 15, grp = lane >> 4;
  int gi = e_lo + blockIdx.x * EB + w * 16 + e16;
  if (gi >= E) gi = E - 1;
  const int e = perm[gi];
  const int snd = eidx[e], rcv = eidx[E + e];
  const float r = elen[e], tt = tdif[e];
  float uu_ = r * 0.2f;
  float u2 = uu_ * uu_, u4 = u2 * u2, u5 = u4 * uu_;
  float cc = 1.0f - 21.0f * u5 + 35.0f * u5 * uu_ - 15.0f * u5 * u2;
  const float cut = (uu_ < 1.0f) ? cc : 0.0f;
  const float lncut = lens[e] * cut;

  // ---- build raw A-fragments (bf16) in registers + stats ----
  short8 raw[9];
  float s1 = 0.f, s2 = 0.f;
#pragma unroll
  for (int kk = 0; kk < 9; ++kk) {
    float v[8];
    if (kk < 4) {
      short8 g = *(const short8*)&ns_bf[(size_t)snd * 128 + kk * 32 + grp * 8];
#pragma unroll
      for (int i = 0; i < 8; i++) v[i] = bf2f(g[i]) * cut;
    } else if (kk < 8) {
      short8 g = *(const short8*)&ns_bf[(size_t)rcv * 128 + (kk - 4) * 32 + grp * 8];
#pragma unroll
      for (int i = 0; i < 8; i++) v[i] = bf2f(g[i]) * cut;
    } else {
      if (grp == 0) {
        const float pref = sqrtf(0.4f);
#pragma unroll
        for (int i = 0; i < 8; i++) {
          float kn = (float)(i + 1) * (PI_F / 5.0f);
          v[i] = pref * __sinf(kn * r) / r * __expf(-kn * kn * tt) * cut;
        }
      } else if (grp == 1) {
        v[0] = lncut;
#pragma unroll
        for (int i = 1; i < 8; i++) v[i] = 0.f;
      } else {
#pragma unroll
        for (int i = 0; i < 8; i++) v[i] = 0.f;
      }
    }
#pragma unroll
    for (int i = 0; i < 8; i++) {
      s1 += v[i]; s2 += v[i] * v[i];
      raw[kk][i] = f2bf(v[i]);
    }
  }
  // stats reduce across lane-groups {l, l^16, l^32, l^48}
  s1 += __shfl_xor(s1, 16); s1 += __shfl_xor(s1, 32);
  s2 += __shfl_xor(s2, 16); s2 += __shfl_xor(s2, 32);
  const float mean = s1 * (1.0f / 265.0f);
  const float var  = (s2 - s1 * mean) * (1.0f / 264.0f);   // ddof=1
  const float mupart = msm0 * mean;
  const float vapart = vsm0 * var;

  __syncthreads();   // norm tables staged

  // ======== MFMA layers ========
  const short8* F = (const short8*)frags;
  const int arow = w * 16 + (lane & 15);
  const int kgrp = (lane >> 4) << 3;

  // ---- layer 1: 288 -> 64, normalize fused per-kk (8-elem window) ----
  f32x4 A0 = {0,0,0,0}, A1 = {0,0,0,0}, A2 = {0,0,0,0}, A3 = {0,0,0,0};
#pragma unroll
  for (int kk = 0; kk < 9; ++kk) {
    const int k0 = kk * 32 + grp * 8;
    short8 a;
#pragma unroll
    for (int h = 0; h < 2; ++h) {
      float4 mu4 = *(const float4*)&smu[k0 + 4 * h];
      float4 va4 = *(const float4*)&sva[k0 + 4 * h];
      float4 w4  = *(const float4*)&sw_[k0 + 4 * h];
      float4 b4  = *(const float4*)&sb_[k0 + 4 * h];
#pragma unroll
      for (int i = 0; i < 4; ++i) {
        float x  = bf2f(raw[kk][4 * h + i]);
        float mu = mupart + ((const float*)&mu4)[i];
        float va = vapart + ((const float*)&va4)[i];
        float rs = __builtin_amdgcn_rsq(va);
        a[4 * h + i] = f2bf(fmaf((x - mu) * rs, ((const float*)&w4)[i], ((const float*)&b4)[i]));
      }
    }
    A0 = __builtin_amdgcn_mfma_f32_16x16x32_bf16(a, F[(kk * 4 + 0) * 64 + lane], A0, 0, 0, 0);
    A1 = __builtin_amdgcn_mfma_f32_16x16x32_bf16(a, F[(kk * 4 + 1) * 64 + lane], A1, 0, 0, 0);
    A2 = __builtin_amdgcn_mfma_f32_16x16x32_bf16(a, F[(kk * 4 + 2) * 64 + lane], A2, 0, 0, 0);
    A3 = __builtin_amdgcn_mfma_f32_16x16x32_bf16(a, F[(kk * 4 + 3) * 64 + lane], A3, 0, 0, 0);
  }
#pragma unroll
  for (int rr = 0; rr < 4; ++rr) {
    int er = w * 16 + ((lane >> 4) << 2) + rr;
    hA[er][ 0 + (lane & 15)] = f2bf(silu_f(A0[rr]));
    hA[er][16 + (lane & 15)] = f2bf(silu_f(A1[rr]));
    hA[er][32 + (lane & 15)] = f2bf(silu_f(A2[rr]));
    hA[er][48 + (lane & 15)] = f2bf(silu_f(A3[rr]));
  }
  __syncthreads();

  // ---- layer 2: 64 -> 64 ----
  A0 = A1 = A2 = A3 = (f32x4){0,0,0,0};
#pragma unroll
  for (int kk = 0; kk < 2; ++kk) {
    short8 a = *(const short8*)&hA[arow][kk * 32 + kgrp];
    A0 = __builtin_amdgcn_mfma_f32_16x16x32_bf16(a, F[(36 + kk * 4 + 0) * 64 + lane], A0, 0, 0, 0);
    A1 = __builtin_amdgcn_mfma_f32_16x16x32_bf16(a, F[(36 + kk * 4 + 1) * 64 + lane], A1, 0, 0, 0);
    A2 = __builtin_amdgcn_mfma_f32_16x16x32_bf16(a, F[(36 + kk * 4 + 2) * 64 + lane], A2, 0, 0, 0);
    A3 = __builtin_amdgcn_mfma_f32_16x16x32_bf16(a, F[(36 + kk * 4 + 3) * 64 + lane], A3, 0, 0, 0);
  }
#pragma unroll
  for (int rr = 0; rr < 4; ++rr) {
    int er = w * 16 + ((lane >> 4) << 2) + rr;
    hB[er][ 0 + (lane & 15)] = f2bf(silu_f(A0[rr]));
    hB[er][16 + (lane & 15)] = f2bf(silu_f(A1[rr]));
    hB[er][32 + (lane & 15)] = f2bf(silu_f(A2[rr]));
    hB[er][48 + (lane & 15)] = f2bf(silu_f(A3[rr]));
  }
  __syncthreads();

  // ---- layer 3: 64 -> 64 ----
  A0 = A1 = A2 = A3 = (f32x4){0,0,0,0};
#pragma unroll
  for (int kk = 0; kk < 2; ++kk) {
    short8 a = *(const short8*)&hB[arow][kk * 32 + kgrp];
    A0 = __builtin_amdgcn_mfma_f32_16x16x32_bf16(a, F[(44 + kk * 4 + 0) * 64 + lane], A0, 0, 0, 0);
    A1 = __builtin_amdgcn_mfma_f32_16x16x32_bf16(a, F[(44 + kk * 4 + 1) * 64 + lane], A1, 0, 0, 0);
    A2 = __builtin_amdgcn_mfma_f32_16x16x32_bf16(a, F[(44 + kk * 4 + 2) * 64 + lane], A2, 0, 0, 0);
    A3 = __builtin_amdgcn_mfma_f32_16x16x32_bf16(a, F[(44 + kk * 4 + 3) * 64 + lane], A3, 0, 0, 0);
  }
  __syncthreads();
#pragma unroll
  for (int rr = 0; rr < 4; ++rr) {
    int er = w * 16 + ((lane >> 4) << 2) + rr;
    hA[er][ 0 + (lane & 15)] = f2bf(silu_f(A0[rr]));
    hA[er][16 + (lane & 15)] = f2bf(silu_f(A1[rr]));
    hA[er][32 + (lane & 15)] = f2bf(silu_f(A2[rr]));
    hA[er][48 + (lane & 15)] = f2bf(silu_f(A3[rr]));
  }
  __syncthreads();

  short8 a40 = *(const short8*)&hA[arow][ 0 + kgrp];
  short8 a41 = *(const short8*)&hA[arow][32 + kgrp];
  const int rowbase = blockIdx.x * EB + w * 16 + ((lane >> 4) << 2);

  // ---- layer 4: 64 -> 512, write tpw (col-packed w0,w1,w2,w3) ----
#pragma unroll
  for (int t = 0; t < 8; ++t) {
    f32x4 W0 = {0,0,0,0}, W1t = {0,0,0,0}, W2t = {0,0,0,0}, W3t = {0,0,0,0};
    W0  = __builtin_amdgcn_mfma_f32_16x16x32_bf16(a40, F[(52 + 0 * 32 + ( 0 + t)) * 64 + lane], W0,  0, 0, 0);
    W0  = __builtin_amdgcn_mfma_f32_16x16x32_bf16(a41, F[(52 + 1 * 32 + ( 0 + t)) * 64 + lane], W0,  0, 0, 0);
    W1t = __builtin_amdgcn_mfma_f32_16x16x32_bf16(a40, F[(52 + 0 * 32 + ( 8 + t)) * 64 + lane], W1t, 0, 0, 0);
    W1t = __builtin_amdgcn_mfma_f32_16x16x32_bf16(a41, F[(52 + 1 * 32 + ( 8 + t)) * 64 + lane], W1t, 0, 0, 0);
    W2t = __builtin_amdgcn_mfma_f32_16x16x32_bf16(a40, F[(52 + 0 * 32 + (16 + t)) * 64 + lane], W2t, 0, 0, 0);
    W2t = __builtin_amdgcn_mfma_f32_16x16x32_bf16(a41, F[(52 + 1 * 32 + (16 + t)) * 64 + lane], W2t, 0, 0, 0);
    W3t = __builtin_amdgcn_mfma_f32_16x16x32_bf16(a40, F[(52 + 0 * 32 + (24 + t)) * 64 + lane], W3t, 0, 0, 0);
    W3t = __builtin_amdgcn_mfma_f32_16x16x32_bf16(a41, F[(52 + 1 * 32 + (24 + t)) * 64 + lane], W3t, 0, 0, 0);

    const int uu = t * 16 + (lane & 15);
#pragma unroll
    for (int rr = 0; rr < 4; ++rr) {
      short4v pk;
      pk[0] = f2bf(W0[rr]); pk[1] = f2bf(W1t[rr]);
      pk[2] = f2bf(W2t[rr]); pk[3] = f2bf(W3t[rr]);
      *(short4v*)(tpw + (size_t)(rowbase + rr) * 512 + uu * 4) = pk;
    }
  }
}

// ---------------------------------------------------------------- gather kernel
// 2 blocks per node (column halves), 64 threads each; pipelined inner loop;
// bf16 M output (out_mfma consumes bf16 anyway).
__global__ __launch_bounds__(64)
void gather_kernel(const int* __restrict__ rs, const int* __restrict__ perm,
                   const int* __restrict__ eidx, const float* __restrict__ eattr,
                   const short4v* __restrict__ suvu,
                   const short* __restrict__ tpw,
                   short* __restrict__ M0b, short* __restrict__ M1b,
                   int e_lo, int e_hi, int E, int writemode)
{
  __shared__ int   s_snd[64];
  __shared__ __align__(16) float s_y[64][4];

  const int n    = blockIdx.x >> 1;
  const int half = blockIdx.x & 1;
  const int tid  = threadIdx.x;
  const int o    = half * 64 + tid;        // column 0..127
  int lo = rs[n], hi = rs[n + 1];
  if (lo < e_lo) lo = e_lo;
  if (hi > e_hi) hi = e_hi;
  if (!writemode && lo >= hi) return;

  float a0 = 0.f, a1 = 0.f;
  float b0 = 0.f, b1 = 0.f, b2 = 0.f;
  float c0 = 0.f, c1 = 0.f, c2 = 0.f;

  for (int base = lo; base < hi; base += 64) {
    const int cnt_ = min(64, hi - base);
    __syncthreads();
    if (tid < cnt_) {
      int e = perm[base + tid];
      s_snd[tid] = eidx[e];
      *(float4*)&s_y[tid][0] = *(const float4*)&eattr[e * 4];
    }
    __syncthreads();
    // software pipeline: prefetch j+1 while computing j
    short4v sv = suvu[(size_t)s_snd[0] * 128 + o];
    short4v pk = *(const short4v*)(tpw + (size_t)(base - e_lo) * 512 + o * 4);
    for (int j = 0; j < cnt_; ++j) {
      short4v sv_n = sv, pk_n = pk;
      if (j + 1 < cnt_) {
        sv_n = suvu[(size_t)s_snd[j + 1] * 128 + o];
        pk_n = *(const short4v*)(tpw + (size_t)(base + j + 1 - e_lo) * 512 + o * 4);
      }
      const float4 y = *(const float4*)&s_y[j][0];
      const float se = bf2f(sv[0]);
      const float v0 = bf2f(sv[1]);
      const float v1 = bf2f(sv[2]);
      const float v2 = bf2f(sv[3]);
      const float w0 = bf2f(pk[0]), w1 = bf2f(pk[1]);
      const float w2 = bf2f(pk[2]), w3 = bf2f(pk[3]);
      const float dot = v0 * y.y + v1 * y.z + v2 * y.w;
      a0 = fmaf(w0 * se, y.x, a0);
      a1 = fmaf(w3, dot, a1);                        // isq3 folded into w3
      const float s1v = w1 * se;
      b0 = fmaf(s1v, y.y, b0); b1 = fmaf(s1v, y.z, b1); b2 = fmaf(s1v, y.w, b2);
      const float vv = w2 * y.x;
      c0 = fmaf(vv, v0, c0); c1 = fmaf(vv, v1, c1); c2 = fmaf(vv, v2, c2);
      sv = sv_n; pk = pk_n;
    }
  }
  short* p0 = M0b + (size_t)n * 256;
  short* p1 = M1b + (size_t)n * 768;
  if (writemode) {
    p0[o] = f2bf(a0); p0[128 + o] = f2bf(a1);
    p1[0 * 256 + o] = f2bf(b0); p1[1 * 256 + o] = f2bf(b1); p1[2 * 256 + o] = f2bf(b2);
    p1[0 * 256 + 128 + o] = f2bf(c0); p1[1 * 256 + 128 + o] = f2bf(c1); p1[2 * 256 + 128 + o] = f2bf(c2);
  } else {
    p0[o] = f2bf(bf2f(p0[o]) + a0); p0[128 + o] = f2bf(bf2f(p0[128 + o]) + a1);
    p1[0 * 256 + o] = f2bf(bf2f(p1[0 * 256 + o]) + b0);
    p1[1 * 256 + o] = f2bf(bf2f(p1[1 * 256 + o]) + b1);
    p1[2 * 256 + o] = f2bf(bf2f(p1[2 * 256 + o]) + b2);
    p1[0 * 256 + 128 + o] = f2bf(bf2f(p1[0 * 256 + 128 + o]) + c0);
    p1[1 * 256 + 128 + o] = f2bf(bf2f(p1[1 * 256 + 128 + o]) + c1);
    p1[2 * 256 + 128 + o] = f2bf(bf2f(p1[2 * 256 + 128 + o]) + c2);
  }
}

// ---------------------------------------------------------------- out MFMA
__global__ __launch_bounds__(128)
void out_mfma(const short* __restrict__ M0b, const short* __restrict__ M1b,
              const short* __restrict__ frags, float* __restrict__ out, int N)
{
  const int tid = threadIdx.x, lane = tid & 63, w = tid >> 6;
  const int nbase = blockIdx.x * 32 + w * 16;
  const int kgrp = (lane >> 4) << 3;
  int nd = nbase + (lane & 15); if (nd >= N) nd = N - 1;

  const short* rowp[4];
  rowp[0] = M0b + (size_t)nd * 256;
  rowp[1] = M1b + (size_t)nd * 768;
  rowp[2] = M1b + (size_t)nd * 768 + 256;
  rowp[3] = M1b + (size_t)nd * 768 + 512;

  f32x4 acc[8][4];
#pragma unroll
  for (int nt = 0; nt < 8; ++nt)
#pragma unroll
    for (int s = 0; s < 4; ++s) acc[nt][s] = (f32x4){0,0,0,0};

  const short8* F = (const short8*)frags;
#pragma unroll
  for (int kc = 0; kc < 8; ++kc) {
    short8 a[4];
#pragma unroll
    for (int s = 0; s < 4; ++s)
      a[s] = *(const short8*)&rowp[s][kc * 32 + kgrp];
#pragma unroll
    for (int nt = 0; nt < 8; ++nt) {
      short8 b0 = F[(212 + kc * 8 + nt) * 64 + lane];
      short8 b1 = F[(276 + kc * 8 + nt) * 64 + lane];
      acc[nt][0] = __builtin_amdgcn_mfma_f32_16x16x32_bf16(a[0], b0, acc[nt][0], 0, 0, 0);
      acc[nt][1] = __builtin_amdgcn_mfma_f32_16x16x32_bf16(a[1], b1, acc[nt][1], 0, 0, 0);
      acc[nt][2] = __builtin_amdgcn_mfma_f32_16x16x32_bf16(a[2], b1, acc[nt][2], 0, 0, 0);
      acc[nt][3] = __builtin_amdgcn_mfma_f32_16x16x32_bf16(a[3], b1, acc[nt][3], 0, 0, 0);
    }
  }

#pragma unroll
  for (int nt = 0; nt < 8; ++nt) {
    const int col = nt * 16 + (lane & 15);
#pragma unroll
    for (int rr = 0; rr < 4; ++rr) {
      int n = nbase + ((lane >> 4) << 2) + rr;
      if (n < N) {
        float4 r;
        r.x = acc[nt][0][rr];
        r.y = acc[nt][1][rr];
        r.z = acc[nt][2][rr];
        r.w = acc[nt][3][rr];
        *(float4*)(out + ((size_t)n * 128 + col) * 4) = r;
      }
    }
  }
}

// ---------------------------------------------------------------- launcher
extern "C" void kernel_launch(void* const* d_in, const int* in_sizes, int n_in,
                              void* d_out, int out_size, void* d_ws, size_t ws_size,
                              hipStream_t stream)
{
  const float* nf   = (const float*)d_in[0];
  const float* eattr= (const float*)d_in[1];
  const float* elen = (const float*)d_in[2];
  const float* tdif = (const float*)d_in[3];
  const float* lens = (const float*)d_in[4];
  const int*   eidx = (const int*)  d_in[5];
  const float* Wsc  = (const float*)d_in[6];
  const float* Wu0  = (const float*)d_in[7];
  const float* Wu1  = (const float*)d_in[8];
  const float* snw  = (const float*)d_in[9];
  const float* snb  = (const float*)d_in[10];
  const float* snmw = (const float*)d_in[11];
  const float* snvw = (const float*)d_in[12];
  const float* snrm = (const float*)d_in[13];
  const float* snrv = (const float*)d_in[14];
  const float* W1   = (const float*)d_in[15];
  const float* W2   = (const float*)d_in[16];
  const float* W3   = (const float*)d_in[17];
  const float* W4   = (const float*)d_in[18];
  const float* Wo0  = (const float*)d_in[19];
  const float* Wo1  = (const float*)d_in[20];

  const int N = in_sizes[0] / 512;
  const int E = in_sizes[1] / 4;

  char* p = (char*)d_ws;
  short*   ns_bf = (short*)p;    p += (size_t)N * 128 * 2;
  short4v* suvu  = (short4v*)p;  p += (size_t)N * 128 * 8;
  short*   M0b   = (short*)p;    p += (size_t)N * 256 * 2;
  short*   M1b   = (short*)p;    p += (size_t)N * 768 * 2;
  float4*  nrm_c = (float4*)p;   p += 266 * 16;
  short*   frags = (short*)p;    p += (size_t)340 * 64 * 8 * 2;
  int* cnt    = (int*)p;         p += (size_t)N * 4;
  int* rs     = (int*)p;         p += (size_t)(N + 1) * 4;
  int* cursor = (int*)p;         p += (size_t)N * 4;
  int* perm   = (int*)p;         p += (size_t)E * 4;
  size_t used = (size_t)(p - (char*)d_ws);
  used = (used + 255) & ~(size_t)255;
  short* tpw = (short*)((char*)d_ws + used);
  size_t avail = (ws_size > used) ? (ws_size - used) : 0;

  long long chunk = (long long)(avail / 1024) & ~31LL;   // edges per chunk (1KB each)
  long long Eup = ((long long)E + 31) & ~31LL;
  if (chunk > Eup) chunk = Eup;
  if (chunk < 32)  chunk = 32;            // last-resort (assumes ws covers it)
  const int writemode = (chunk >= Eup) ? 1 : 0;

  if (!writemode)
    hipMemsetAsync(M0b, 0, (size_t)1024 * N * sizeof(short), stream);
  hipMemsetAsync(cnt, 0, (size_t)N * sizeof(int), stream);

  const int hist_blocks = (E + 255) / 256;
  prep_fused<<<dim3(87 + hist_blocks), dim3(256), 0, stream>>>(
      W1, W2, W3, W4, Wsc, Wu0, Wu1, Wo0, Wo1,
      snw, snb, snmw, snvw, snrm, snrv, eidx, frags, nrm_c, cnt, E);
  node_mfma<<<dim3((N + 31) / 32), dim3(128), 0, stream>>>(nf, frags, ns_bf, suvu, N);
  scan_kernel<<<dim3(1), dim3(1024), 0, stream>>>(cnt, rs, cursor, N);
  scatter_kernel<<<dim3((E + 255) / 256), dim3(256), 0, stream>>>(eidx, cursor, perm, E);

  for (long long lo = 0; lo < E; lo += chunk) {
    int n_e = (int)(((long long)E - lo < chunk) ? ((long long)E - lo) : chunk);
    int blocks = (n_e + EB - 1) / EB;
    edge_mlp<<<dim3(blocks), dim3(128), 0, stream>>>(
        elen, tdif, lens, eidx, nrm_c, ns_bf, frags, perm, tpw, (int)lo, E);
    gather_kernel<<<dim3(2 * N), dim3(64), 0, stream>>>(
        rs, perm, eidx, eattr, suvu, tpw, M0b, M1b, (int)lo, (int)(lo + n_e), E, writemode);
  }

  out_mfma<<<dim3((N + 31) / 32), dim3(128), 0, stream>>>(M0b, M1b, frags, (float*)d_out, N);
}